// Round 1
// baseline (70.995 us; speedup 1.0000x reference)
//
#include <hip/hip_runtime.h>

// Problem: B=4, P=12, H=W=32, K_STEP=12, NUM_CELLS=1024, TE_DEPTH=168, F=1192.
//
// Dtypes (established rounds 0-2 of prior session): ALL float inputs fp32, TE
// int32, OUTPUT fp32. The test's "bf16" label / k=8 floor threshold is
// comparison policy (bf16-rounded ref), not buffer dtype.
//
// Algorithm: one-hot matmuls collapse to row-gather + add:
//   logits[b,p,cell,j]  = W_trans[te_idx(b,p)][j] + W_trans[168+cell][j]
//   restart_logit       = W_restart[te_idx] + W_restart[168+cell]
//   bias_w              = W_bias[te_idx]    + W_bias[168+cell]
// Stencil: cell (h,w) receives channel d of neighbor at offset (dr,dc)_d;
// trans_prob is loop-invariant -> 8 incoming-edge weights per cell cached in
// registers; x grid double-buffered in padded LDS (zero border = jnp.pad).
//
// THIS ROUND (latency/LDS-overhead attack; problem is ~5 MB I/O => 0.8 us at
// HBM ceiling, so we are nowhere near memory-bound; parallelism capped at 48
// independent (b,p) slices => per-CU latency is the lever):
//  * 256 threads x 4 adjacent cells/thread (was 1024 x 1):
//      - stencil: 3x ds_read_b128 + fused edge-pair reads + 1 ds_write_b128
//        per thread per iter => ~28 LDS wave-insts/CU/iter vs 144 (5x less),
//        all <=2-way bank aliasing (free) with 40-float padded row stride.
//      - barrier width 16 waves -> 4 waves.
//  * trans_prob LDS transposed to [d][h*33+w]: 33-stride kills the 8-way
//    bank conflicts of the old tp[cell*8+j] layout (publish AND gather).
//  * float4 global loads (Wt/Wr/Wb/X) and stores (trans/rp/x/Y).
//  * res[4][13] register-resident (no per-iter vmcnt drain at barriers);
//    __launch_bounds__(256,1) lifts the 128-VGPR cap of the 1024-thr version.

namespace {
constexpr int PP   = 12;      // P
constexpr int NC   = 1024;    // 32*32
constexpr int TED  = 168;     // TE_DEPTH
constexpr int KS   = 12;      // K_STEP
constexpr int PADW = 40;      // padded x-grid row stride (floats); cell (h,w)
                              // lives at [(h+1)*40 + (w+4)] => b128-aligned,
                              // row stride 40 => bank +8/row (conflict-free)
constexpr int GSZ  = 34 * PADW;   // 1360 floats per grid buffer
constexpr int TPR  = 33;          // tpT row stride => bank +1/row
constexpr int TPD  = 32 * TPR;    // 1056 floats per direction plane
// flat output offsets (elements), return order:
// Y(4096) | x(49152) | trans(393216) | restart(49152) | results(638976)
constexpr long O_X   = 4096;
constexpr long O_TP  = 53248;
constexpr long O_RP  = 446464;
constexpr long O_RES = 495616;
}

__global__ __launch_bounds__(256, 1) void rwr_fused(
    const float* __restrict__ X,     // (B,P,32,32,1) fp32
    const int* __restrict__ TE,      // (B,24,2) int32
    const float* __restrict__ Wt,    // (1192,8) fp32
    const float* __restrict__ Wr,    // (1192,1) fp32
    const float* __restrict__ Wb,    // (1192,1) fp32
    float* __restrict__ out)         // fp32
{
    __shared__ __align__(16) float tpT[8 * TPD];   // [d][h*33+w], 33 KB
    __shared__ __align__(16) float xg[2 * GSZ];    // double-buffered padded grid

    const int bp    = blockIdx.x;        // b*12 + p
    const int bIdx  = bp / PP;
    const int p     = bp - bIdx * PP;
    const int t     = threadIdx.x;       // 0..255
    const int h     = t >> 3;            // 0..31
    const int w0    = (t & 7) << 2;      // 0,4,...,28
    const int cell0 = (h << 5) + w0;
    const long gci0 = (long)bp * NC + cell0;

    // zero both padded grids (borders stay 0 forever = jnp.pad)
    {
        const float4 z4 = make_float4(0.f, 0.f, 0.f, 0.f);
        float4* xg4 = (float4*)xg;
        for (int i = t; i < (2 * GSZ) / 4; i += 256) xg4[i] = z4;
    }

    const int te = TE[(bIdx * 24 + p) * 2 + 0] * 24 + TE[(bIdx * 24 + p) * 2 + 1];

    // te-row broadcast (L2/L1 hit after first lane)
    float teRow[8];
    #pragma unroll
    for (int j = 0; j < 8; ++j) teRow[j] = Wt[te * 8 + j];

    // per-cell softmax over 8 transition logits (4 cells/thread)
    float pr[4][8];
    #pragma unroll
    for (int c = 0; c < 4; ++c) {
        const float4 a = *(const float4*)&Wt[(TED + cell0 + c) * 8];
        const float4 d = *(const float4*)&Wt[(TED + cell0 + c) * 8 + 4];
        float l[8] = {a.x, a.y, a.z, a.w, d.x, d.y, d.z, d.w};
        float m = -1e30f;
        #pragma unroll
        for (int j = 0; j < 8; ++j) { l[j] += teRow[j]; m = fmaxf(m, l[j]); }
        float s = 0.f;
        #pragma unroll
        for (int j = 0; j < 8; ++j) { l[j] = __expf(l[j] - m); s += l[j]; }
        const float inv = 1.f / s;
        #pragma unroll
        for (int j = 0; j < 8; ++j) pr[c][j] = l[j] * inv;
    }

    // restart prob, bias weight, x0 — all float4 loads
    const float4 wr4 = *(const float4*)&Wr[TED + cell0];
    const float4 wb4 = *(const float4*)&Wb[TED + cell0];
    const float4 x04 = *(const float4*)&X[(long)bp * NC + cell0];
    const float  wrTe = Wr[te], wbTe = Wb[te];
    const float wrArr[4] = {wr4.x, wr4.y, wr4.z, wr4.w};
    const float wbArr[4] = {wb4.x, wb4.y, wb4.z, wb4.w};
    const float x0Arr[4] = {x04.x, x04.y, x04.z, x04.w};

    float rp_[4], xb_[4], x_[4];
    float res[4][13];
    #pragma unroll
    for (int c = 0; c < 4; ++c) {
        rp_[c] = 1.f / (1.f + __expf(-(wrTe + wrArr[c])));
        xb_[c] = (wbTe + wbArr[c]) * x0Arr[c];
        x_[c]  = x0Arr[c];
        res[c][0] = x0Arr[c];
    }

    __syncthreads();   // grid zeroing complete

    // publish trans_prob (transposed, 33-stride => <=2-way banks) + initial x
    #pragma unroll
    for (int c = 0; c < 4; ++c)
        #pragma unroll
        for (int j = 0; j < 8; ++j)
            tpT[j * TPD + h * TPR + (w0 + c)] = pr[c][j];
    *(float4*)&xg[(h + 1) * PADW + w0 + 4] = make_float4(x_[0], x_[1], x_[2], x_[3]);

    // stream the loop-invariant outputs now (drained once at next barrier)
    #pragma unroll
    for (int c = 0; c < 4; ++c) {
        *(float4*)&out[O_TP + (gci0 + c) * 8]     = make_float4(pr[c][0], pr[c][1], pr[c][2], pr[c][3]);
        *(float4*)&out[O_TP + (gci0 + c) * 8 + 4] = make_float4(pr[c][4], pr[c][5], pr[c][6], pr[c][7]);
    }
    *(float4*)&out[O_RP + gci0] = make_float4(rp_[0], rp_[1], rp_[2], rp_[3]);

    __syncthreads();   // tpT + initial grid visible

    // incoming-edge weights: cell receives channel d from neighbor at +delta_d.
    // OOB neighbors read x=0 from the padded border, so the weight is moot
    // (clamp index to 0 to avoid OOB LDS read).
    const int drr[8] = {-1,-1,-1, 0, 0, 1, 1, 1};
    const int dcc[8] = {-1, 0, 1,-1, 1,-1, 0, 1};
    float wn[4][8];
    #pragma unroll
    for (int c = 0; c < 4; ++c) {
        const int wc = w0 + c;
        #pragma unroll
        for (int d = 0; d < 8; ++d) {
            const int nh = h + drr[d], nw = wc + dcc[d];
            const bool ok = ((unsigned)nh < 32u) && ((unsigned)nw < 32u);
            const int idx = ok ? (d * TPD + nh * TPR + nw) : 0;
            wn[c][d] = tpT[idx];
        }
    }

    float* cur = xg;
    float* nxt = xg + GSZ;
    const int rA = h * PADW + w0;          // padded row h   = cell row h-1
    const int rB = rA + PADW;              // padded row h+1 = cell row h
    const int rC = rB + PADW;              // padded row h+2 = cell row h+1
    #pragma unroll
    for (int k = 0; k < KS; ++k) {
        // 6-wide row windows: cols (w0-1 .. w0+4) = padded (w0+3 .. w0+8)
        float T[6], M[6], Bt[6];
        { const float4 v = *(const float4*)&cur[rA + 4];
          T[0]=cur[rA+3]; T[1]=v.x; T[2]=v.y; T[3]=v.z; T[4]=v.w; T[5]=cur[rA+8]; }
        { const float4 v = *(const float4*)&cur[rB + 4];
          M[0]=cur[rB+3]; M[1]=v.x; M[2]=v.y; M[3]=v.z; M[4]=v.w; M[5]=cur[rB+8]; }
        { const float4 v = *(const float4*)&cur[rC + 4];
          Bt[0]=cur[rC+3]; Bt[1]=v.x; Bt[2]=v.y; Bt[3]=v.z; Bt[4]=v.w; Bt[5]=cur[rC+8]; }

        #pragma unroll
        for (int c = 0; c < 4; ++c) {
            const float xt = wn[c][0]*T[c]  + wn[c][1]*T[c+1]  + wn[c][2]*T[c+2]
                           + wn[c][3]*M[c]  + wn[c][4]*M[c+2]
                           + wn[c][5]*Bt[c] + wn[c][6]*Bt[c+1] + wn[c][7]*Bt[c+2];
            const float xv = (1.f - rp_[c]) * xt + rp_[c] * x_[c] + xb_[c];
            x_[c] = xv;
            res[c][k + 1] = xv;
        }
        *(float4*)&nxt[rB + 4] = make_float4(x_[0], x_[1], x_[2], x_[3]);
        { float* tsw = cur; cur = nxt; nxt = tsw; }
        __syncthreads();
    }

    // ---- epilogue: x, results, Y ----
    *(float4*)&out[O_X + gci0] = make_float4(x_[0], x_[1], x_[2], x_[3]);
    #pragma unroll
    for (int c = 0; c < 4; ++c)
        #pragma unroll
        for (int k = 0; k <= KS; ++k)
            out[O_RES + (gci0 + c) * 13 + k] = res[c][k];
    if (p == PP - 1)
        *(float4*)&out[(long)bIdx * NC + cell0] = make_float4(x_[0], x_[1], x_[2], x_[3]);
}

extern "C" void kernel_launch(void* const* d_in, const int* in_sizes, int n_in,
                              void* d_out, int out_size, void* d_ws, size_t ws_size,
                              hipStream_t stream) {
    const float* X  = (const float*)d_in[0];
    const int*   TE = (const int*)d_in[1];
    const float* Wt = (const float*)d_in[2];
    const float* Wr = (const float*)d_in[3];
    const float* Wb = (const float*)d_in[4];
    float* out = (float*)d_out;

    rwr_fused<<<dim3(4 * PP), dim3(256), 0, stream>>>(X, TE, Wt, Wr, Wb, out);
}

// Round 2
// 67.320 us; speedup vs baseline: 1.0546x; 1.0546x over previous
//
#include <hip/hip_runtime.h>

// Problem: B=4, P=12, H=W=32, K_STEP=12, NUM_CELLS=1024, TE_DEPTH=168, F=1192.
//
// Dtypes (established in prior session): ALL float inputs fp32, TE int32,
// OUTPUT fp32. The test's "bf16" label / k=8 floor threshold is comparison
// policy (bf16-rounded ref), not buffer dtype.
//
// Algorithm: one-hot matmuls collapse to row-gather + add:
//   logits[b,p,cell,j]  = W_trans[te_idx(b,p)][j] + W_trans[168+cell][j]
//   restart_logit       = W_restart[te_idx] + W_restart[168+cell]
//   bias_w              = W_bias[te_idx]    + W_bias[168+cell]
// Stencil: cell (h,w) receives channel d of neighbor at offset (dr,dc)_d;
// trans_prob loop-invariant -> 8 incoming-edge weights cached in registers;
// x grid double-buffered in padded LDS (zero border = jnp.pad).
//
// SESSION EVIDENCE (rounds 0-1): dur_us is insensitive to kernel structure
// (1024thr/16LDS-ops-per-cell-iter = 68.8 us; 256thr/4x-vectorized = 71.0 us).
// All top-5 rocprof dispatches are the harness's 268 MB re-poison fill at
// ~40 us / 83% HBM peak. => timed path = fill + launch overhead + small
// kernel (<40 us, modeled ~5 us). This round: third structural point to
// confirm the floor, with every micro-cost honestly minimized:
//  * 1024 threads (16 waves: best latency hiding for cold prologue loads and
//    epilogue streaming; round-0 config was the empirically better one).
//  * tpT transposed [d][h*33+w]: publish and gather both <=2-way banks
//    (old tp[cell*8+j] publish was 8-way conflicted).
//  * x grid row stride 36: all stencil ds_read/ds_write <=2-way (free).
//  * border-only zeroing (132 elems/buffer) merged with the publish barrier:
//    one barrier + one full-grid fill pass removed.
//  * TE loaded first (heads the 3-deep dependent cold-miss chain
//    TE -> te -> W*[te]); independent per-cell W loads issue in parallel.
//  * float4 loads (Wt cell rows) and float4 stores (trans_prob).

namespace {
constexpr int PP   = 12;          // P
constexpr int NC   = 1024;        // 32*32
constexpr int TED  = 168;         // TE_DEPTH
constexpr int KS   = 12;          // K_STEP
constexpr int PADW = 36;          // padded x-grid row stride: bank +4/row
constexpr int GSZ  = 34 * PADW;   // 1224 floats per grid buffer
constexpr int TPR  = 33;          // tpT row stride: bank +1/row
constexpr int TPD  = 32 * TPR;    // 1056 floats per direction plane
// flat output offsets (elements), return order:
// Y(4096) | x(49152) | trans(393216) | restart(49152) | results(638976)
constexpr long O_X   = 4096;
constexpr long O_TP  = 53248;
constexpr long O_RP  = 446464;
constexpr long O_RES = 495616;
}

__global__ __launch_bounds__(1024) void rwr_fused(
    const float* __restrict__ X,     // (B,P,32,32,1) fp32
    const int* __restrict__ TE,      // (B,24,2) int32
    const float* __restrict__ Wt,    // (1192,8) fp32
    const float* __restrict__ Wr,    // (1192,1) fp32
    const float* __restrict__ Wb,    // (1192,1) fp32
    float* __restrict__ out)         // fp32
{
    __shared__ __align__(16) float tpT[8 * TPD];   // 33 KB
    __shared__ __align__(16) float xg[2 * GSZ];    // 9.6 KB, double-buffered

    const int bp   = blockIdx.x;          // b*12 + p
    const int bIdx = bp / PP;
    const int p    = bp - bIdx * PP;
    const int t    = threadIdx.x;         // 0..1023
    const int h    = t >> 5;
    const int w    = t & 31;
    const long gci = (long)bp * NC + t;

    // ---- head of the longest dependent-miss chain: issue first ----
    const int te = TE[(bIdx * 24 + p) * 2 + 0] * 24 + TE[(bIdx * 24 + p) * 2 + 1];

    // ---- border-only zeroing (reads touch rows 0..33, cols 1..34 only;
    //      interior cells are always written before read) ----
    if (t < 264) {
        const int bsel = t / 132, r = t % 132;
        float* g = xg + bsel * GSZ;
        int idx;
        if (r < 34)       idx = 1 + r;                        // row 0
        else if (r < 68)  idx = 33 * PADW + 1 + (r - 34);     // row 33
        else if (r < 100) idx = (1 + (r - 68)) * PADW + 1;    // col 1
        else              idx = (1 + (r - 100)) * PADW + 34;  // col 34
        g[idx] = 0.f;
    }

    // ---- independent per-cell loads (issue in parallel with te chain) ----
    const float4 wtA = *(const float4*)&Wt[(TED + t) * 8];
    const float4 wtB = *(const float4*)&Wt[(TED + t) * 8 + 4];
    const float  wrC = Wr[TED + t];
    const float  wbC = Wb[TED + t];
    const float  x0  = X[gci];

    // ---- te-row (dependent on te; broadcast, L1-hit after first lane) ----
    float l[8] = {wtA.x, wtA.y, wtA.z, wtA.w, wtB.x, wtB.y, wtB.z, wtB.w};
    float m = -1e30f;
    #pragma unroll
    for (int j = 0; j < 8; ++j) { l[j] += Wt[te * 8 + j]; m = fmaxf(m, l[j]); }
    float s = 0.f;
    #pragma unroll
    for (int j = 0; j < 8; ++j) { l[j] = __expf(l[j] - m); s += l[j]; }
    const float inv = 1.f / s;
    float pr[8];
    #pragma unroll
    for (int j = 0; j < 8; ++j) pr[j] = l[j] * inv;

    const float rp    = 1.f / (1.f + __expf(-(Wr[te] + wrC)));
    const float xbias = (Wb[te] + wbC) * x0;

    // ---- publish trans_prob (transposed; bank = h+w mod 32, <=2-way)
    //      and initial grid ----
    #pragma unroll
    for (int j = 0; j < 8; ++j) tpT[j * TPD + h * TPR + w] = pr[j];
    xg[(h + 1) * PADW + (w + 2)] = x0;

    // ---- stream loop-invariant outputs (no barrier needed for stores) ----
    *(float4*)&out[O_TP + gci * 8]     = make_float4(pr[0], pr[1], pr[2], pr[3]);
    *(float4*)&out[O_TP + gci * 8 + 4] = make_float4(pr[4], pr[5], pr[6], pr[7]);
    out[O_RP + gci] = rp;

    __syncthreads();   // borders + tpT + initial grid visible

    // incoming-edge weights: cell receives channel d from neighbor at delta_d;
    // OOB neighbors read x=0 from the padded border (weight value moot,
    // clamp index to 0 to stay in-bounds).
    const int drr[8] = {-1,-1,-1, 0, 0, 1, 1, 1};
    const int dcc[8] = {-1, 0, 1,-1, 1,-1, 0, 1};
    float wn[8];
    #pragma unroll
    for (int d = 0; d < 8; ++d) {
        const int nh = h + drr[d], nw = w + dcc[d];
        const bool ok = ((unsigned)nh < 32u) && ((unsigned)nw < 32u);
        const int idx = ok ? (d * TPD + nh * TPR + nw) : 0;
        wn[d] = tpT[idx];
    }

    float res[KS + 1];
    res[0] = x0;
    float x = x0;
    float* cur = xg;
    float* nxt = xg + GSZ;
    const int c0 = (h + 1) * PADW + (w + 2);   // this cell in padded grid
    #pragma unroll
    for (int k = 0; k < KS; ++k) {
        float xt = 0.f;
        #pragma unroll
        for (int d = 0; d < 8; ++d)
            xt += wn[d] * cur[c0 + drr[d] * PADW + dcc[d]];
        x = (1.f - rp) * xt + rp * x + xbias;
        res[k + 1] = x;
        nxt[c0] = x;
        float* tsw = cur; cur = nxt; nxt = tsw;
        __syncthreads();
    }

    // ---- epilogue: x, results, Y ----
    out[O_X + gci] = x;
    #pragma unroll
    for (int k = 0; k <= KS; ++k) out[O_RES + gci * 13 + k] = res[k];
    if (p == PP - 1) out[(long)bIdx * NC + t] = x;   // Y = x[:, -1]
}

extern "C" void kernel_launch(void* const* d_in, const int* in_sizes, int n_in,
                              void* d_out, int out_size, void* d_ws, size_t ws_size,
                              hipStream_t stream) {
    const float* X  = (const float*)d_in[0];
    const int*   TE = (const int*)d_in[1];
    const float* Wt = (const float*)d_in[2];
    const float* Wr = (const float*)d_in[3];
    const float* Wb = (const float*)d_in[4];
    float* out = (float*)d_out;

    rwr_fused<<<dim3(4 * PP), dim3(1024), 0, stream>>>(X, TE, Wt, Wr, Wb, out);
}